// Round 4
// baseline (125.465 us; speedup 1.0000x reference)
//
#include <hip/hip_runtime.h>
#include <math.h>

// AdderNet fused forward v4: u16 fixed-point SAD, weights streamed via scalar
// cache (s_load) from d_ws, acts read once per spatial position.
//
// q(v) = round((v+8)*1024) u16; |q(a)-q(w)| = 1024*|a-w| (+-1). Pad = q(0).
//
// d_ws (uint words): QW1[96]@0   [o16][kh3][{(w0,w1),(w2,0)}]
//                    QW2[2304]@96   [m8][o32][pk9]  word=(w[o][2m][pk],w[o][2m+1][pk])
//                    QW3[2304]@2400 [m2 16][o16][pk9]
//                    QW4[720]@4704  [m8][o10][pk9]
//
// Main kernel: 4 images/block, 1024 blocks, 256 thr, 2 blocks/CU (69.5 KB LDS).
//  sX [2016]: [img4][y28][stride18], word = (x[2k],x[2k+1]) quantized
//  sA1[9600]: [plane32=(m8,img4)][y15][stride20], word = ch-pair (a[2m],a[2m+1])
//             after stage2: part[2560]@0, A3[576]@2560, l4[160]@3136, logits@3296
//  sA2[5760]: [plane64=(m2*4+img)][y9][stride10], ch-pair words

#if defined(__has_builtin)
#if __has_builtin(__builtin_amdgcn_sad_u16)
#define HAS_SAD 1
#endif
#endif

__device__ __forceinline__ unsigned sadu16(unsigned a, unsigned b, unsigned acc) {
#ifdef HAS_SAD
  return __builtin_amdgcn_sad_u16(a, b, acc);
#else
  int al = (int)(a & 0xFFFFu), ah = (int)(a >> 16);
  int bl = (int)(b & 0xFFFFu), bh = (int)(b >> 16);
  return acc + (unsigned)(al > bl ? al - bl : bl - al)
             + (unsigned)(ah > bh ? ah - bh : bh - ah);
#endif
}

__device__ __forceinline__ unsigned quant(float v) {
  return (unsigned)fmaf(v, 1024.0f, 8192.5f);  // v >= -8 by construction
}

#define QPAD 0x20002000u

// ---------------- weight prep: quantize + repack into d_ws ----------------
__global__ void adder_prep(const float* __restrict__ w1, const float* __restrict__ w2,
                           const float* __restrict__ w3, const float* __restrict__ w4,
                           unsigned* __restrict__ qw) {
  int k = blockIdx.x * 256 + threadIdx.x;
  if (k < 96) {
    int o = k / 6, r = k % 6, kh = r >> 1, h = r & 1;
    const float* p = w1 + o * 9 + kh * 3;
    qw[k] = h ? quant(p[2]) : (quant(p[0]) | (quant(p[1]) << 16));
  } else if (k < 2400) {
    int k2 = k - 96, m = k2 / 288, r = k2 % 288, o = r / 9, pk = r % 9;
    int s = o * 144 + 2 * m * 9 + pk;
    qw[k] = quant(w2[s]) | (quant(w2[s + 9]) << 16);
  } else if (k < 4704) {
    int k3 = k - 2400, m2 = k3 / 144, r = k3 % 144, o = r / 9, pk = r % 9;
    int s = o * 288 + 2 * m2 * 9 + pk;
    qw[k] = quant(w3[s]) | (quant(w3[s + 9]) << 16);
  } else if (k < 5424) {
    int k4 = k - 4704, m = k4 / 90, r = k4 % 90, o = r / 9, pk = r % 9;
    int s = o * 144 + 2 * m * 9 + pk;
    qw[k] = quant(w4[s]) | (quant(w4[s + 9]) << 16);
  }
}

__global__ __launch_bounds__(256, 2) void adder_main(
    const float* __restrict__ gx,
    const unsigned* __restrict__ qw,
    float* __restrict__ gout)
{
  __shared__ __align__(16) unsigned sA1[9600];
  __shared__ __align__(16) unsigned sA2[5760];
  __shared__ __align__(16) unsigned sX[2016];

  const int t = threadIdx.x;
  const int b = blockIdx.x;

  // ---------------- stage 0: stage inputs, init pads ----------------
  for (int k = t; k < 1568; k += 256) {     // 4 img * 392 pair-words
    int img = k / 392, r = k % 392, y = r / 14, xw = r % 14;
    const float2 v = *(const float2*)(gx + (size_t)(4 * b + img) * 784 + y * 28 + 2 * xw);
    sX[img * 504 + y * 18 + xw] = quant(v.x - 0.5f) | (quant(v.y - 0.5f) << 16);
  }
  for (int k = t; k < 448; k += 256) {      // zero-fill X row tails (words 14..17)
    int img = k / 112, r = k % 112, y = r / 4, c = r % 4;
    sX[img * 504 + y * 18 + 14 + c] = 0u;
  }
  {
    uint4 pad4 = make_uint4(QPAD, QPAD, QPAD, QPAD);
    uint4* p = (uint4*)sA1;
    for (int k = t; k < 2400; k += 256) p[k] = pad4;
    uint4* p2 = (uint4*)sA2;
    for (int k = t; k < 1440; k += 256) p2[k] = pad4;
  }
  __syncthreads();

  // ---------------- stage 1: L1 [16,13,13] ----------------
  if (t < 208) {
    const int i = t >> 4, img = (t >> 2) & 3, jq = t & 3;  // j = 4jq+jj
    unsigned r[3][5], mw[3][4];
#pragma unroll
    for (int kh = 0; kh < 3; ++kh) {
      const unsigned* rp = sX + img * 504 + (2 * i + kh) * 18 + 4 * jq;
#pragma unroll
      for (int c = 0; c < 5; ++c) r[kh][c] = rp[c];
#pragma unroll
      for (int c = 0; c < 4; ++c) mw[kh][c] = r[kh][c + 1] & 0xFFFFu;
    }
#pragma unroll 1
    for (int op = 0; op < 8; ++op) {        // output-channel pairs
      const unsigned* w = qw + op * 12;     // 12 uniform words -> s_load
      unsigned a0[4], a1[4];
#pragma unroll
      for (int jj = 0; jj < 4; ++jj) { a0[jj] = 0u; a1[jj] = 0u; }
#pragma unroll
      for (int kh = 0; kh < 3; ++kh) {
        unsigned wa01 = w[kh * 2], wa2 = w[kh * 2 + 1];
        unsigned wb01 = w[6 + kh * 2], wb2 = w[6 + kh * 2 + 1];
#pragma unroll
        for (int jj = 0; jj < 4; ++jj) {
          a0[jj] = sadu16(r[kh][jj], wa01, a0[jj]);
          a0[jj] = sadu16(mw[kh][jj], wa2, a0[jj]);
          a1[jj] = sadu16(r[kh][jj], wb01, a1[jj]);
          a1[jj] = sadu16(mw[kh][jj], wb2, a1[jj]);
        }
      }
      unsigned* dst = sA1 + (op * 4 + img) * 300 + (i + 1) * 20 + 4 * jq + 1;
#pragma unroll
      for (int jj = 0; jj < 4; ++jj) {
        if (4 * jq + jj < 13) {
          float f0 = fmaxf(fmaf((float)a0[jj], -1.0f / 4096.0f, 2.5f), 0.0f);
          float f1 = fmaxf(fmaf((float)a1[jj], -1.0f / 4096.0f, 2.5f), 0.0f);
          dst[jj] = quant(f0) | (quant(f1) << 16);
        }
      }
    }
  }
  __syncthreads();

  // ---------------- stage 2: L2 [32,7,7], all 32 o per thread ----------------
  if (t < 196) {
    const int img = t / 49, pos = t % 49, i = pos / 7, j = pos % 7;
    unsigned acc[32];
#pragma unroll
    for (int o = 0; o < 32; ++o) acc[o] = 0u;
    const unsigned* qw2 = qw + 96;
#pragma unroll 1
    for (int m = 0; m < 8; ++m) {
      const unsigned* plane = sA1 + (m * 4 + img) * 300;
      unsigned p[3][3];
#pragma unroll
      for (int kh = 0; kh < 3; ++kh)
#pragma unroll
        for (int c = 0; c < 3; ++c)
          p[kh][c] = plane[(2 * i + kh) * 20 + 2 * j + c];
      const unsigned* wm = qw2 + m * 288;   // uniform -> s_load
#pragma unroll
      for (int oct = 0; oct < 4; ++oct) {
        const unsigned* ws = wm + oct * 72;
#pragma unroll
        for (int oo = 0; oo < 8; ++oo) {
          const unsigned* w9 = ws + oo * 9;
          unsigned a = acc[oct * 8 + oo];
#pragma unroll
          for (int kh = 0; kh < 3; ++kh)
#pragma unroll
            for (int c = 0; c < 3; ++c)
              a = sadu16(p[kh][c], w9[kh * 3 + c], a);
          acc[oct * 8 + oo] = a;
        }
      }
    }
#pragma unroll
    for (int m2 = 0; m2 < 16; ++m2) {
      float f0 = fmaxf(fmaf((float)acc[2 * m2],     -1.0f / 8192.0f, 16.25f), 0.0f);
      float f1 = fmaxf(fmaf((float)acc[2 * m2 + 1], -1.0f / 8192.0f, 16.25f), 0.0f);
      sA2[(m2 * 4 + img) * 90 + (i + 1) * 10 + (j + 1)] = quant(f0) | (quant(f1) << 16);
    }
  }
  __syncthreads();

  // ---------------- stage 3: L3 [16,4,4], 16 o per thread, 2 ch-groups ----------------
  if (t < 128) {
    const int mg = t >> 6, img = (t >> 4) & 3, pos = t & 15, i = pos >> 2, j = pos & 3;
    unsigned acc[16];
#pragma unroll
    for (int o = 0; o < 16; ++o) acc[o] = 0u;
    const unsigned* qw3 = qw + 2400;
#pragma unroll 1
    for (int mm = 0; mm < 8; ++mm) {
      const int m2 = mg * 8 + mm;
      const unsigned* plane = sA2 + (m2 * 4 + img) * 90;
      unsigned p[3][3];
#pragma unroll
      for (int kh = 0; kh < 3; ++kh)
#pragma unroll
        for (int c = 0; c < 3; ++c)
          p[kh][c] = plane[(2 * i + kh) * 10 + 2 * j + c];
      const unsigned* wm = qw3 + m2 * 144;  // uniform -> s_load
#pragma unroll
      for (int oct = 0; oct < 2; ++oct) {
        const unsigned* ws = wm + oct * 72;
#pragma unroll
        for (int oo = 0; oo < 8; ++oo) {
          const unsigned* w9 = ws + oo * 9;
          unsigned a = acc[oct * 8 + oo];
#pragma unroll
          for (int kh = 0; kh < 3; ++kh)
#pragma unroll
            for (int c = 0; c < 3; ++c)
              a = sadu16(p[kh][c], w9[kh * 3 + c], a);
          acc[oct * 8 + oo] = a;
        }
      }
    }
    unsigned* pp = sA1 + ((mg * 4 + img) * 16 + pos) * 20;  // 80B stride, 16B aligned
#pragma unroll
    for (int u = 0; u < 4; ++u)
      *(uint4*)(pp + u * 4) = make_uint4(acc[4 * u], acc[4 * u + 1], acc[4 * u + 2], acc[4 * u + 3]);
  }
  __syncthreads();

  // reduce ch-groups -> A3 pair words @ sA1[2560..]
  if (t < 64) {
    const int img = t >> 4, pos = t & 15;
    const unsigned* P = sA1 + (img * 16 + pos) * 20;
    const unsigned* Q = P + 1280;           // mg=1 offset = 4*16*20
#pragma unroll
    for (int m = 0; m < 8; ++m) {
      unsigned s0 = P[2 * m] + Q[2 * m];
      unsigned s1 = P[2 * m + 1] + Q[2 * m + 1];
      float f0 = fmaxf(fmaf((float)s0, -1.0f / 16384.0f, 17.5f), 0.0f);
      float f1 = fmaxf(fmaf((float)s1, -1.0f / 16384.0f, 17.5f), 0.0f);
      sA1[2560 + (img * 8 + m) * 18 + pos] = quant(f0) | (quant(f1) << 16);
    }
  }
  __syncthreads();

  // ---------------- stage 4: L4 + log_softmax ----------------
  if (t < 160) {
    const int img = t / 40, r = t % 40, o = r / 4, mq = r % 4;
    const unsigned* qw4 = qw + 4704;
    unsigned acc = 0u;
#pragma unroll
    for (int mm = 0; mm < 2; ++mm) {
      const int m = mq * 2 + mm;
      const unsigned* a3 = sA1 + 2560 + (img * 8 + m) * 18;
      const unsigned* w9 = qw4 + (m * 10 + o) * 9;  // uniform per (o,mq)? o,mq vary per lane
#pragma unroll
      for (int kh = 0; kh < 3; ++kh)
#pragma unroll
        for (int kw = 0; kw < 3; ++kw)
          acc = sadu16(a3[kh * 4 + kw], w9[kh * 3 + kw], acc);
    }
    sA1[3136 + t] = acc;
  }
  __syncthreads();
  if (t < 40) {
    const int img = t / 10, o = t % 10;
    const unsigned* P = sA1 + 3136 + img * 40 + o * 4;
    unsigned s = P[0] + P[1] + P[2] + P[3];
    ((float*)sA1)[3296 + t] = -(float)s * (1.0f / 1024.0f);
  }
  __syncthreads();
  if (t < 40) {
    const int img = t / 10, o = t % 10;
    const float* lg = (const float*)sA1 + 3296 + img * 10;
    float mx = lg[0];
#pragma unroll
    for (int k = 1; k < 10; ++k) mx = fmaxf(mx, lg[k]);
    float sum = 0.0f;
#pragma unroll
    for (int k = 0; k < 10; ++k) sum += __expf(lg[k] - mx);
    gout[(size_t)(4 * b + img) * 10 + o] = lg[o] - mx - __logf(sum);
  }
}

extern "C" void kernel_launch(void* const* d_in, const int* in_sizes, int n_in,
                              void* d_out, int out_size, void* d_ws, size_t ws_size,
                              hipStream_t stream) {
  const float* x  = (const float*)d_in[0];
  const float* w1 = (const float*)d_in[1];
  const float* w2 = (const float*)d_in[2];
  const float* w3 = (const float*)d_in[3];
  const float* w4 = (const float*)d_in[4];
  unsigned* qw = (unsigned*)d_ws;           // 5424 words = 21.7 KB
  float* out = (float*)d_out;
  adder_prep<<<22, 256, 0, stream>>>(w1, w2, w3, w4, qw);
  adder_main<<<1024, 256, 0, stream>>>(x, qw, out);
}

// Round 5
// 119.331 us; speedup vs baseline: 1.0514x; 1.0514x over previous
//
#include <hip/hip_runtime.h>
#include <math.h>

// AdderNet fused forward v5: u16 fixed-point SAD, weights via scalar cache
// (s_load) from d_ws, acts read once per spatial position, 3 blocks/CU.
//
// q(v) = round((v+8)*1024) u16; |q(a)-q(w)| = 1024*|a-w| (+-1). Pad = q(0).
//
// d_ws (uint words): QW1[96]@0      [o16][kh3][{(w0,w1),(w2,0)}]
//                    QW2[2304]@96   [m8][o32][pk9]  word=(w[o][2m][pk],w[o][2m+1][pk])
//                    QW3[2304]@2400 [m2 16][o16][pk9]
//                    QW4[720]@4704  [m8][o10][pk9]
//
// Main: 4 img/block, 1024 blocks, 256 thr, 3 blocks/CU (LDS 53,376 B).
//  sA1[8160]: [plane32=(m8,img4)]*255, row stride 17 (15 rows x 15 cells), ch-pair words
//             after stage2: part[3072]@0 (stride 12/thread), A3[544]@3104 (stride 17),
//             l4[160]@3712, logits(float)[40]@3968
//  sU[5184] : stage 0-1: X[img4][y28][stride17] (476/img)
//             stage 2+ : A2[plane64=(m2*4+img)][y9][x9] (packed 81/plane)

#if defined(__has_builtin)
#if __has_builtin(__builtin_amdgcn_sad_u16)
#define HAS_SAD 1
#endif
#endif

__device__ __forceinline__ unsigned sadu16(unsigned a, unsigned b, unsigned acc) {
#ifdef HAS_SAD
  return __builtin_amdgcn_sad_u16(a, b, acc);
#else
  int al = (int)(a & 0xFFFFu), ah = (int)(a >> 16);
  int bl = (int)(b & 0xFFFFu), bh = (int)(b >> 16);
  return acc + (unsigned)(al > bl ? al - bl : bl - al)
             + (unsigned)(ah > bh ? ah - bh : bh - ah);
#endif
}

__device__ __forceinline__ unsigned quant(float v) {
  return (unsigned)fmaf(v, 1024.0f, 8192.5f);  // v >= -8 by construction
}

#define QPAD 0x20002000u

// ---------------- weight prep: quantize + repack into d_ws ----------------
__global__ void adder_prep(const float* __restrict__ w1, const float* __restrict__ w2,
                           const float* __restrict__ w3, const float* __restrict__ w4,
                           unsigned* __restrict__ qw) {
  int k = blockIdx.x * 256 + threadIdx.x;
  if (k < 96) {
    int o = k / 6, r = k % 6, kh = r >> 1, h = r & 1;
    const float* p = w1 + o * 9 + kh * 3;
    qw[k] = h ? quant(p[2]) : (quant(p[0]) | (quant(p[1]) << 16));
  } else if (k < 2400) {
    int k2 = k - 96, m = k2 / 288, r = k2 % 288, o = r / 9, pk = r % 9;
    int s = o * 144 + 2 * m * 9 + pk;
    qw[k] = quant(w2[s]) | (quant(w2[s + 9]) << 16);
  } else if (k < 4704) {
    int k3 = k - 2400, m2 = k3 / 144, r = k3 % 144, o = r / 9, pk = r % 9;
    int s = o * 288 + 2 * m2 * 9 + pk;
    qw[k] = quant(w3[s]) | (quant(w3[s + 9]) << 16);
  } else if (k < 5424) {
    int k4 = k - 4704, m = k4 / 90, r = k4 % 90, o = r / 9, pk = r % 9;
    int s = o * 144 + 2 * m * 9 + pk;
    qw[k] = quant(w4[s]) | (quant(w4[s + 9]) << 16);
  }
}

__global__ __launch_bounds__(256, 3) void adder_main(
    const float* __restrict__ gx,
    const unsigned* __restrict__ qw,
    float* __restrict__ gout)
{
  __shared__ __align__(16) unsigned sA1[8160];
  __shared__ __align__(16) unsigned sU[5184];

  const int t = threadIdx.x;
  const int b = blockIdx.x;

  // ---------------- stage 0: stage input image, init A1 borders ----------------
  for (int k = t; k < 1568; k += 256) {     // 4 img * 392 pair-words
    int img = k / 392, r = k % 392, y = r / 14, xw = r % 14;
    const float2 v = *(const float2*)(gx + (size_t)(4 * b + img) * 784 + y * 28 + 2 * xw);
    sU[img * 476 + y * 17 + xw] = quant(v.x - 0.5f) | (quant(v.y - 0.5f) << 16);
  }
  // A1 border cells only (56 per plane x 32 planes)
  for (int k = t; k < 1792; k += 256) {
    int plane = k / 56, c = k % 56;
    int y, x;
    if (c < 15)      { y = 0;      x = c; }
    else if (c < 30) { y = 14;     x = c - 15; }
    else if (c < 43) { y = c - 29; x = 0; }
    else             { y = c - 42; x = 14; }
    sA1[plane * 255 + y * 17 + x] = QPAD;
  }
  __syncthreads();

  // ---------------- stage 1: L1 [16,13,13] ----------------
  if (t < 208) {
    const int i = t >> 4, img = (t >> 2) & 3, jq = t & 3;  // j = 4jq+jj
    unsigned r[3][5], mw[3][4];
#pragma unroll
    for (int kh = 0; kh < 3; ++kh) {
      const unsigned* rp = sU + img * 476 + (2 * i + kh) * 17 + 4 * jq;
#pragma unroll
      for (int c = 0; c < 5; ++c) r[kh][c] = rp[c];
#pragma unroll
      for (int c = 0; c < 4; ++c) mw[kh][c] = r[kh][c + 1] & 0xFFFFu;
    }
#pragma unroll 1
    for (int op = 0; op < 8; ++op) {        // output-channel pairs
      const unsigned* w = qw + op * 12;     // uniform -> s_load
      unsigned a0[4], a1[4];
#pragma unroll
      for (int jj = 0; jj < 4; ++jj) { a0[jj] = 0u; a1[jj] = 0u; }
#pragma unroll
      for (int kh = 0; kh < 3; ++kh) {
        unsigned wa01 = w[kh * 2], wa2 = w[kh * 2 + 1];
        unsigned wb01 = w[6 + kh * 2], wb2 = w[6 + kh * 2 + 1];
#pragma unroll
        for (int jj = 0; jj < 4; ++jj) {
          a0[jj] = sadu16(r[kh][jj], wa01, a0[jj]);
          a0[jj] = sadu16(mw[kh][jj], wa2, a0[jj]);
          a1[jj] = sadu16(r[kh][jj], wb01, a1[jj]);
          a1[jj] = sadu16(mw[kh][jj], wb2, a1[jj]);
        }
      }
      unsigned* dst = sA1 + (op * 4 + img) * 255 + (i + 1) * 17 + 4 * jq + 1;
#pragma unroll
      for (int jj = 0; jj < 4; ++jj) {
        if (4 * jq + jj < 13) {
          float f0 = fmaxf(fmaf((float)a0[jj], -1.0f / 4096.0f, 2.5f), 0.0f);
          float f1 = fmaxf(fmaf((float)a1[jj], -1.0f / 4096.0f, 2.5f), 0.0f);
          dst[jj] = quant(f0) | (quant(f1) << 16);
        }
      }
    }
  }
  __syncthreads();

  // ---------------- stage 2: L2 [32,7,7], all 32 o per thread ----------------
  if (t < 196) {
    const int img = t / 49, pos = t % 49, i = pos / 7, j = pos % 7;
    unsigned acc[32];
#pragma unroll
    for (int o = 0; o < 32; ++o) acc[o] = 0u;
    const unsigned* qw2 = qw + 96;
#pragma unroll 1
    for (int m = 0; m < 8; ++m) {
      const unsigned* plane = sA1 + (m * 4 + img) * 255;
      unsigned p[3][3];
#pragma unroll
      for (int kh = 0; kh < 3; ++kh)
#pragma unroll
        for (int c = 0; c < 3; ++c)
          p[kh][c] = plane[(2 * i + kh) * 17 + 2 * j + c];
      const unsigned* wm = qw2 + m * 288;   // uniform -> s_load
#pragma unroll
      for (int oct = 0; oct < 4; ++oct) {
        const unsigned* ws = wm + oct * 72;
#pragma unroll
        for (int oo = 0; oo < 8; ++oo) {
          const unsigned* w9 = ws + oo * 9;
          unsigned a = acc[oct * 8 + oo];
#pragma unroll
          for (int kh = 0; kh < 3; ++kh)
#pragma unroll
            for (int c = 0; c < 3; ++c)
              a = sadu16(p[kh][c], w9[kh * 3 + c], a);
          acc[oct * 8 + oo] = a;
        }
      }
    }
#pragma unroll
    for (int m2 = 0; m2 < 16; ++m2) {
      float f0 = fmaxf(fmaf((float)acc[2 * m2],     -1.0f / 8192.0f, 16.25f), 0.0f);
      float f1 = fmaxf(fmaf((float)acc[2 * m2 + 1], -1.0f / 8192.0f, 16.25f), 0.0f);
      sU[(m2 * 4 + img) * 81 + (i + 1) * 9 + (j + 1)] = quant(f0) | (quant(f1) << 16);
    }
  } else {
    // A2 border cells <- q(0): 32 cells x 64 planes, by the idle threads.
    // sX region is dead (stage-1 barrier passed); disjoint from interior writes.
    for (int k = t - 196; k < 2048; k += 60) {
      int plane = k >> 5, c = k & 31;
      int y, x;
      if (c < 9)       { y = 0; x = c; }
      else if (c < 18) { y = 8; x = c - 9; }
      else if (c < 25) { y = c - 17; x = 0; }
      else             { y = c - 24; x = 8; }
      sU[plane * 81 + y * 9 + x] = QPAD;
    }
  }
  __syncthreads();

  // ---------------- stage 3: L3 [16,4,4], 256 threads (mg2 x og2) ----------------
  {
    const int pos = t & 15, img = (t >> 4) & 3, og = (t >> 6) & 1, mg = t >> 7;
    const int i = pos >> 2, j = pos & 3;
    unsigned acc[8];
#pragma unroll
    for (int o = 0; o < 8; ++o) acc[o] = 0u;
    const unsigned* qw3 = qw + 2400;
#pragma unroll 1
    for (int mm = 0; mm < 8; ++mm) {
      const int m2 = mg * 8 + mm;
      const unsigned* plane = sU + (m2 * 4 + img) * 81;
      unsigned p[3][3];
#pragma unroll
      for (int kh = 0; kh < 3; ++kh)
#pragma unroll
        for (int c = 0; c < 3; ++c)
          p[kh][c] = plane[(2 * i + kh) * 9 + 2 * j + c];
      const unsigned* ws = qw3 + m2 * 144 + og * 72;  // uniform -> s_load
#pragma unroll
      for (int oo = 0; oo < 8; ++oo) {
        const unsigned* w9 = ws + oo * 9;
        unsigned a = acc[oo];
#pragma unroll
        for (int kh = 0; kh < 3; ++kh)
#pragma unroll
          for (int c = 0; c < 3; ++c)
            a = sadu16(p[kh][c], w9[kh * 3 + c], a);
        acc[oo] = a;
      }
    }
    unsigned* pp = sA1 + t * 12;            // 48B stride: aligned, ~2-way banks
    *(uint4*)(pp)     = make_uint4(acc[0], acc[1], acc[2], acc[3]);
    *(uint4*)(pp + 4) = make_uint4(acc[4], acc[5], acc[6], acc[7]);
  }
  __syncthreads();

  // reduce mg-groups -> A3 pair words @ sA1[3104..], plane stride 17
  if (t < 64) {
    const int img = t >> 4, pos = t & 15;
#pragma unroll
    for (int m = 0; m < 8; ++m) {
      const int og = m >> 2, oo = 2 * (m & 3);
      const int b0 = ((og << 6) | (img << 4) | pos) * 12;
      unsigned s0 = sA1[b0 + oo]     + sA1[b0 + 1536 + oo];
      unsigned s1 = sA1[b0 + oo + 1] + sA1[b0 + 1536 + oo + 1];
      float f0 = fmaxf(fmaf((float)s0, -1.0f / 16384.0f, 17.5f), 0.0f);
      float f1 = fmaxf(fmaf((float)s1, -1.0f / 16384.0f, 17.5f), 0.0f);
      sA1[3104 + (img * 8 + m) * 17 + pos] = quant(f0) | (quant(f1) << 16);
    }
  }
  __syncthreads();

  // ---------------- stage 4: L4 + log_softmax ----------------
  if (t < 160) {
    const int img = t / 40, r = t % 40, o = r / 4, mq = r % 4;
    const unsigned* qw4 = qw + 4704;
    unsigned acc = 0u;
#pragma unroll
    for (int mm = 0; mm < 2; ++mm) {
      const int m = mq * 2 + mm;
      const unsigned* a3 = sA1 + 3104 + (img * 8 + m) * 17;
      const unsigned* w9 = qw4 + (m * 10 + o) * 9;   // per-lane -> vector load
#pragma unroll
      for (int kh = 0; kh < 3; ++kh)
#pragma unroll
        for (int kw = 0; kw < 3; ++kw)
          acc = sadu16(a3[kh * 4 + kw], w9[kh * 3 + kw], acc);
    }
    sA1[3712 + t] = acc;
  }
  __syncthreads();
  if (t < 40) {
    const int img = t / 10, o = t % 10;
    const unsigned* P = sA1 + 3712 + img * 40 + o * 4;
    unsigned s = P[0] + P[1] + P[2] + P[3];
    ((float*)sA1)[3968 + t] = -(float)s * (1.0f / 1024.0f);
  }
  __syncthreads();
  if (t < 40) {
    const int img = t / 10, o = t % 10;
    const float* lg = (const float*)sA1 + 3968 + img * 10;
    float mx = lg[0];
#pragma unroll
    for (int k = 1; k < 10; ++k) mx = fmaxf(mx, lg[k]);
    float sum = 0.0f;
#pragma unroll
    for (int k = 0; k < 10; ++k) sum += __expf(lg[k] - mx);
    gout[(size_t)(4 * b + img) * 10 + o] = lg[o] - mx - __logf(sum);
  }
}

extern "C" void kernel_launch(void* const* d_in, const int* in_sizes, int n_in,
                              void* d_out, int out_size, void* d_ws, size_t ws_size,
                              hipStream_t stream) {
  const float* x  = (const float*)d_in[0];
  const float* w1 = (const float*)d_in[1];
  const float* w2 = (const float*)d_in[2];
  const float* w3 = (const float*)d_in[3];
  const float* w4 = (const float*)d_in[4];
  unsigned* qw = (unsigned*)d_ws;           // 5424 words = 21.7 KB
  float* out = (float*)d_out;
  adder_prep<<<22, 256, 0, stream>>>(w1, w2, w3, w4, qw);
  adder_main<<<1024, 256, 0, stream>>>(x, qw, out);
}